// Round 6
// baseline (744.777 us; speedup 1.0000x reference)
//
#include <hip/hip_runtime.h>
#include <hip/hip_bf16.h>
#include <math.h>

// Problem constants (fixed by the reference: B=4,S=2048,H=1024,D=4096)
#define H_DIM 1024
#define NBASIS 8
#define K_DIM 9216                // 8*H (spline, k=h*8+j) + H (silu, k=8192+h)
#define K_SILU 8192
#define BM 256                    // block tile (M and O)
#define BK 64                     // K tile (bf16 elements)
#define NKT (K_DIM / BK)          // 144 (even)

typedef __bf16 bf16x8 __attribute__((ext_vector_type(8)));
typedef float f32x4 __attribute__((ext_vector_type(4)));
typedef unsigned short u16x8 __attribute__((ext_vector_type(8)));
typedef unsigned short u16x4 __attribute__((ext_vector_type(4)));
typedef unsigned short u16x2 __attribute__((ext_vector_type(2)));

__device__ __forceinline__ unsigned short f2bf(float f) {
    __hip_bfloat16 h = __float2bfloat16(f);   // RNE
    return __builtin_bit_cast(unsigned short, h);
}

// Cox-de Boor cubic, knots g[i] = (i-3)*0.4f - 1.0f (fp32, exactly as the
// reference; arithmetic and order identical to the verified r0-r5 kernels).
__device__ __forceinline__ void spline_bases(float v, float* __restrict__ b8) {
    float b[11];
#pragma unroll
    for (int i = 0; i < 11; ++i) {
        const float gi  = (float)(i - 3) * 0.4f + (-1.0f);
        const float gi1 = (float)(i - 2) * 0.4f + (-1.0f);
        b[i] = (v >= gi && v < gi1) ? 1.0f : 0.0f;
    }
#pragma unroll
    for (int k = 1; k <= 3; ++k) {
#pragma unroll
        for (int i = 0; i + k < 11; ++i) {
            const float gi   = (float)(i - 3) * 0.4f + (-1.0f);
            const float gi1  = (float)(i - 2) * 0.4f + (-1.0f);
            const float gik  = (float)(i + k - 3) * 0.4f + (-1.0f);
            const float gik1 = (float)(i + k - 2) * 0.4f + (-1.0f);
            float left  = (v - gi)   * (1.0f / (gik - gi));
            float right = (gik1 - v) * (1.0f / (gik1 - gi1));
            b[i] = left * b[i] + right * b[i + 1];
        }
    }
#pragma unroll
    for (int j = 0; j < NBASIS; ++j) b8[j] = b[j];
}

// ---------------------------------------------------------------------------
// Fused prep kernel (unchanged from round 4/5)
// ---------------------------------------------------------------------------
__global__ void prep_fused(const float* __restrict__ x,
                           const float* __restrict__ bw,
                           const float* __restrict__ sw,
                           const float* __restrict__ ss,
                           unsigned short* __restrict__ A,
                           unsigned short* __restrict__ Bm,
                           int nABlk) {
    if ((int)blockIdx.x < nABlk) {
        // ---- A path: idx = 4*t .. 4*t+3, all same row n (H % 4 == 0) ------
        const int t   = blockIdx.x * 256 + threadIdx.x;
        const int idx = t * 4;
        const int n   = idx >> 10;
        const int h   = idx & (H_DIM - 1);
        const float4 xv = *reinterpret_cast<const float4*>(x + idx);
        const float vs[4] = {xv.x, xv.y, xv.z, xv.w};

        u16x8 packs[4];
        u16x4 silus;
#pragma unroll
        for (int e = 0; e < 4; ++e) {
            const float v = vs[e];
            float b8[NBASIS];
            spline_bases(v, b8);
#pragma unroll
            for (int j = 0; j < NBASIS; ++j) packs[e][j] = f2bf(b8[j]);
            silus[e] = f2bf(v / (1.0f + __expf(-v)));
        }
        const size_t rowBase = (size_t)n * K_DIM;
        u16x8* dst = reinterpret_cast<u16x8*>(A + rowBase + (size_t)h * 8);
#pragma unroll
        for (int e = 0; e < 4; ++e) dst[e] = packs[e];
        *reinterpret_cast<u16x4*>(A + rowBase + K_SILU + h) = silus;
    } else {
        // ---- B path: idx = 2*t .. 2*t+1, same row o (H % 2 == 0) ----------
        const int t   = (blockIdx.x - nABlk) * 256 + threadIdx.x;
        const int idx = t * 2;
        const int o   = idx >> 10;
        const int h   = idx & (H_DIM - 1);
        const float4* p = reinterpret_cast<const float4*>(sw + (size_t)idx * 8);
        const float2 scv = *reinterpret_cast<const float2*>(ss + idx);
        const float2 bwv = *reinterpret_cast<const float2*>(bw + idx);
        const float sc[2] = {scv.x, scv.y};

        u16x8 packs[2];
#pragma unroll
        for (int e = 0; e < 2; ++e) {
            float4 w0 = p[e * 2], w1 = p[e * 2 + 1];
            packs[e][0] = f2bf(w0.x * sc[e]); packs[e][1] = f2bf(w0.y * sc[e]);
            packs[e][2] = f2bf(w0.z * sc[e]); packs[e][3] = f2bf(w0.w * sc[e]);
            packs[e][4] = f2bf(w1.x * sc[e]); packs[e][5] = f2bf(w1.y * sc[e]);
            packs[e][6] = f2bf(w1.z * sc[e]); packs[e][7] = f2bf(w1.w * sc[e]);
        }
        const size_t rowBase = (size_t)o * K_DIM;
        u16x8* dst = reinterpret_cast<u16x8*>(Bm + rowBase + (size_t)h * 8);
        dst[0] = packs[0];
        dst[1] = packs[1];
        u16x2 bwp; bwp[0] = f2bf(bwv.x); bwp[1] = f2bf(bwv.y);
        *reinterpret_cast<u16x2*>(Bm + rowBase + K_SILU + h) = bwp;
    }
}

// ---------------------------------------------------------------------------
// Kernel 3: C = gelu(A @ B^T) — 256x256 tile, 8-wave, counted-vmcnt schedule,
// chunk-XOR conflict-free LDS, setprio, bijective XCD swizzle.
// Round-6 change vs r5 (497 us, MfmaUtil 56): 4 phases per iteration (was 8),
// one barrier each. Each phase = 2 quadrants = 32 MFMA vs <=16 ds_reads, so
// the read burst amortizes over 2x MFMA work and rendezvous count halves.
// Counted-vmcnt ledger (halves = 2 gloads each), re-derived for this shape:
//   Ph1 reads A0,B0,B1(t)   [buf0]; stages A1(t+1)->buf1   (last read prev Ph4)
//   Ph2 reads A1(t)         [buf0]; stages A0,B0,B1(t+2)->buf0 (last read Ph1)
//        WAIT vmcnt(6): 14 outstanding, oldest 8 = tile t+1 complete.
//   Ph3 reads A0,B0,B1(t+1) [buf1]; stages A1(t+2)->buf0   (last read Ph2)
//   Ph4 reads A1(t+1)       [buf1]; stages A0,B0,B1(t+3)->buf1 (last read Ph3)
//        WAIT vmcnt(6): oldest 8 = tile t+2 complete.
// Every stage target's last read is in the previous phase, across a barrier.
// Tail clamp keeps issue counts uniform (dup stages land in already-read
// regions). Prologue leaves exactly the steady-state 3 halves in flight.
// ---------------------------------------------------------------------------
#define FENCE()      asm volatile("" ::: "memory")
#define BARRIER()    do { FENCE(); __builtin_amdgcn_s_barrier(); FENCE(); } while (0)
#define WAIT_VM6()   asm volatile("s_waitcnt vmcnt(6)" ::: "memory")

// Load NF*2 fragments (NF row-blocks x kk=0,1) from one LDS half-tile.
// Chunk-XOR swizzle: logical chunk c at row r lives in slot c ^ (r&7).
template<int NF>
__device__ __forceinline__ void load_frags(const unsigned short* hp, int rbase,
                                           int l16, int quad, bf16x8* f) {
#pragma unroll
    for (int i = 0; i < NF; ++i)
#pragma unroll
        for (int kk = 0; kk < 2; ++kk)
            f[i * 2 + kk] = *reinterpret_cast<const bf16x8*>(
                &hp[(rbase + i * 16 + l16) * 64 +
                    ((((kk << 2) + quad) ^ (l16 & 7)) << 3)]);
}

template<int QA, int QB>
__device__ __forceinline__ void mfma_quad(const bf16x8* aF, const bf16x8* bF,
                                          f32x4 (&acc)[8][4]) {
#pragma unroll
    for (int kk = 0; kk < 2; ++kk)          // kk OUTER: no dependent pairs
#pragma unroll
        for (int m2 = 0; m2 < 4; ++m2)
#pragma unroll
            for (int n2 = 0; n2 < 2; ++n2)
                acc[QA * 4 + m2][QB * 2 + n2] =
                    __builtin_amdgcn_mfma_f32_16x16x32_bf16(
                        aF[m2 * 2 + kk], bF[n2 * 2 + kk],
                        acc[QA * 4 + m2][QB * 2 + n2], 0, 0, 0);
}

__global__ __launch_bounds__(512, 2) void gemm_kan(
    const unsigned short* __restrict__ A,
    const unsigned short* __restrict__ B,
    float* __restrict__ out, int M, int D) {

    // 2 dbuf x {A0,A1,B0,B1} halves of 128x64 bf16 = 128 KiB
    __shared__ __align__(16) unsigned short lds[2][4][128 * 64];

    const int tid  = threadIdx.x;
    const int lane = tid & 63;
    const int w    = tid >> 6;          // wave 0..7
    const int wr   = w >> 2;            // 0..1  (M half)
    const int wc   = w & 3;             // 0..3  (N quarter)
    const int quad = lane >> 4, l16 = lane & 15;

    // T1: bijective XCD swizzle (nwg = 512, 512 % 8 == 0)
    const int nwg = gridDim.x;
    const int cpx = nwg >> 3;
    int bid = blockIdx.x;
    bid = (bid & 7) * cpx + (bid >> 3);
    const int nOB  = D / BM;            // 16
    const int mBlk = bid / nOB;
    const int oBlk = bid % nOB;

    // ---- staging geometry (verified: 0 bank conflicts) --------------------
    // Half-tile = 128 rows x 64 bf16 (16 KiB); wave w stages rows
    // [w*16, w*16+16) as 2 x global_load_lds (1024 B each, linear dest).
    // Source pre-swizzled: global chunk (lane&7)^(lane>>3) -> slot lane&7.
    // A-half q = rows {wr*128 + q*64 + [0,64)}; B-half q = {wc*64 + q*32 + [0,32)}.
    const int sub = lane >> 3;
    const int cg  = ((lane & 7) ^ sub) * 8;
    const unsigned short *sA[2][2], *sB[2][2];
#pragma unroll
    for (int h = 0; h < 2; ++h)
#pragma unroll
        for (int l = 0; l < 2; ++l) {
            const int r  = w * 16 + l * 8 + sub;          // 0..127
            const int gA = mBlk * BM + (r >> 6) * 128 + h * 64 + (r & 63);
            const int gB = oBlk * BM + (r >> 5) * 64  + h * 32 + (r & 31);
            sA[h][l] = A + (size_t)gA * K_DIM + cg;
            sB[h][l] = B + (size_t)gB * K_DIM + cg;
        }
    const int ldsOff = w * 1024;        // elements; +l*512 per load

    auto stageA = [&](int db, int h, int kt) {
#pragma unroll
        for (int l = 0; l < 2; ++l)
            __builtin_amdgcn_global_load_lds(
                (const __attribute__((address_space(1))) void*)(sA[h][l] + (size_t)kt * BK),
                (__attribute__((address_space(3))) void*)(&lds[db][h][ldsOff + l * 512]),
                16, 0, 0);
    };
    auto stageB = [&](int db, int h, int kt) {
#pragma unroll
        for (int l = 0; l < 2; ++l)
            __builtin_amdgcn_global_load_lds(
                (const __attribute__((address_space(1))) void*)(sB[h][l] + (size_t)kt * BK),
                (__attribute__((address_space(3))) void*)(&lds[db][2 + h][ldsOff + l * 512]),
                16, 0, 0);
    };

    f32x4 acc[8][4];
#pragma unroll
    for (int i = 0; i < 8; ++i)
#pragma unroll
        for (int j = 0; j < 4; ++j)
            acc[i][j] = (f32x4){0.f, 0.f, 0.f, 0.f};
    bf16x8 aF[8], bF0[4], bF1[4];

    // ---- prologue: tile0 (all 4 halves)->buf0 + {A0,B0,B1}(1)->buf1 -------
    stageA(0, 0, 0); stageA(0, 1, 0); stageB(0, 0, 0); stageB(0, 1, 0);
    stageA(1, 0, 1); stageB(1, 0, 1); stageB(1, 1, 1);
    WAIT_VM6();                          // tile0 complete; 3 halves in flight
    BARRIER();

    // ---- main loop: 2 K-tiles / iteration, 4 phases, ONE barrier each -----
    for (int it = 0; it < NKT / 2; ++it) {
        const int t  = it << 1;                          // buf0 tile
        const int t2 = (t + 2 < NKT) ? t + 2 : NKT - 1;  // clamp keeps vmcnt
        const int t3 = (t + 3 < NKT) ? t + 3 : NKT - 1;  // counts uniform

        // Ph1: quads (0,0),(0,1) of t (buf0); stage A1(t+1)->buf1.A1
        stageA(1, 1, t + 1);
        load_frags<4>(&lds[0][0][0], wr * 64, l16, quad, aF);
        load_frags<2>(&lds[0][2][0], wc * 32, l16, quad, bF0);
        load_frags<2>(&lds[0][3][0], wc * 32, l16, quad, bF1);
        FENCE();
        __builtin_amdgcn_s_setprio(1);
        mfma_quad<0, 0>(aF, bF0, acc);
        mfma_quad<0, 1>(aF, bF1, acc);
        __builtin_amdgcn_s_setprio(0);
        BARRIER();

        // Ph2: quads (1,1),(1,0) of t; stage A0,B0,B1(t+2)->buf0
        stageA(0, 0, t2); stageB(0, 0, t2); stageB(0, 1, t2);
        load_frags<4>(&lds[0][1][0], wr * 64, l16, quad, aF);
        FENCE();
        __builtin_amdgcn_s_setprio(1);
        mfma_quad<1, 1>(aF, bF1, acc);
        mfma_quad<1, 0>(aF, bF0, acc);
        __builtin_amdgcn_s_setprio(0);
        WAIT_VM6();                      // tile t+1 fully staged
        BARRIER();

        // Ph3: quads (0,0),(0,1) of t+1 (buf1); stage A1(t+2)->buf0.A1
        stageA(0, 1, t2);
        load_frags<4>(&lds[1][0][0], wr * 64, l16, quad, aF);
        load_frags<2>(&lds[1][2][0], wc * 32, l16, quad, bF0);
        load_frags<2>(&lds[1][3][0], wc * 32, l16, quad, bF1);
        FENCE();
        __builtin_amdgcn_s_setprio(1);
        mfma_quad<0, 0>(aF, bF0, acc);
        mfma_quad<0, 1>(aF, bF1, acc);
        __builtin_amdgcn_s_setprio(0);
        BARRIER();

        // Ph4: quads (1,1),(1,0) of t+1; stage A0,B0,B1(t+3)->buf1
        stageA(1, 0, t3); stageB(1, 0, t3); stageB(1, 1, t3);
        load_frags<4>(&lds[1][1][0], wr * 64, l16, quad, aF);
        FENCE();
        __builtin_amdgcn_s_setprio(1);
        mfma_quad<1, 1>(aF, bF1, acc);
        mfma_quad<1, 0>(aF, bF0, acc);
        __builtin_amdgcn_s_setprio(0);
        WAIT_VM6();                      // tile t+2 fully staged
        BARRIER();
    }
    asm volatile("s_waitcnt vmcnt(0)" ::: "memory");  // drain tail prefetch

    // ---- epilogue: exact (erf) GELU, fp32 store ---------------------------
    const int mBase = mBlk * BM + wr * 128;
    const int oBase = oBlk * BM + wc * 64 + l16;
#pragma unroll
    for (int mi = 0; mi < 8; ++mi) {
#pragma unroll
        for (int ni = 0; ni < 4; ++ni) {
            const int o = oBase + ni * 16;
#pragma unroll
            for (int r = 0; r < 4; ++r) {
                const int m = mBase + mi * 16 + quad * 4 + r;
                float v = acc[mi][ni][r];
                float gv = 0.5f * v * (1.0f + erff(v * 0.70710678118654752f));
                out[(size_t)m * D + o] = gv;
            }
        }
    }
}

// ---------------------------------------------------------------------------
extern "C" void kernel_launch(void* const* d_in, const int* in_sizes, int n_in,
                              void* d_out, int out_size, void* d_ws, size_t ws_size,
                              hipStream_t stream) {
    const float* x  = (const float*)d_in[0];   // (B,S,H)
    const float* bw = (const float*)d_in[1];   // (D,H)
    const float* sw = (const float*)d_in[2];   // (D,H,8)
    const float* ss = (const float*)d_in[3];   // (D,H)
    float* out = (float*)d_out;

    const int M = in_sizes[0] / H_DIM;         // 8192
    const int D = in_sizes[1] / H_DIM;         // 4096

    unsigned short* Aws = (unsigned short*)d_ws;              // M x K bf16
    unsigned short* Bws = Aws + (size_t)M * K_DIM;            // D x K bf16

    const int nABlk = (M * H_DIM / 4) / 256;   // 8192 (exact: M*H % 1024 == 0)
    const int nBBlk = (D * H_DIM / 2) / 256;   // 8192 (exact)
    prep_fused<<<nABlk + nBBlk, 256, 0, stream>>>(x, bw, sw, ss, Aws, Bws, nABlk);

    dim3 grid((M / BM) * (D / BM));            // 32*16 = 512 blocks
    gemm_kan<<<grid, 512, 0, stream>>>(Aws, Bws, out, M, D);
}

// Round 7
// 726.325 us; speedup vs baseline: 1.0254x; 1.0254x over previous
//
#include <hip/hip_runtime.h>
#include <hip/hip_bf16.h>
#include <math.h>

// Problem constants (fixed by the reference: B=4,S=2048,H=1024,D=4096)
#define H_DIM 1024
#define NBASIS 8
#define K_DIM 9216                // 8*H (spline, k=h*8+j) + H (silu, k=8192+h)
#define K_SILU 8192
#define BM 256                    // block tile (M and O)
#define BK 64                     // K tile (bf16 elements)
#define NKT (K_DIM / BK)          // 144 (even)

typedef __bf16 bf16x8 __attribute__((ext_vector_type(8)));
typedef float f32x4 __attribute__((ext_vector_type(4)));
typedef unsigned short u16x8 __attribute__((ext_vector_type(8)));
typedef unsigned short u16x4 __attribute__((ext_vector_type(4)));
typedef unsigned short u16x2 __attribute__((ext_vector_type(2)));

__device__ __forceinline__ unsigned short f2bf(float f) {
    __hip_bfloat16 h = __float2bfloat16(f);   // RNE
    return __builtin_bit_cast(unsigned short, h);
}

// Cox-de Boor cubic, knots g[i] = (i-3)*0.4f - 1.0f (fp32, exactly as the
// reference; arithmetic and order identical to the verified r0-r6 kernels).
__device__ __forceinline__ void spline_bases(float v, float* __restrict__ b8) {
    float b[11];
#pragma unroll
    for (int i = 0; i < 11; ++i) {
        const float gi  = (float)(i - 3) * 0.4f + (-1.0f);
        const float gi1 = (float)(i - 2) * 0.4f + (-1.0f);
        b[i] = (v >= gi && v < gi1) ? 1.0f : 0.0f;
    }
#pragma unroll
    for (int k = 1; k <= 3; ++k) {
#pragma unroll
        for (int i = 0; i + k < 11; ++i) {
            const float gi   = (float)(i - 3) * 0.4f + (-1.0f);
            const float gi1  = (float)(i - 2) * 0.4f + (-1.0f);
            const float gik  = (float)(i + k - 3) * 0.4f + (-1.0f);
            const float gik1 = (float)(i + k - 2) * 0.4f + (-1.0f);
            float left  = (v - gi)   * (1.0f / (gik - gi));
            float right = (gik1 - v) * (1.0f / (gik1 - gi1));
            b[i] = left * b[i] + right * b[i + 1];
        }
    }
#pragma unroll
    for (int j = 0; j < NBASIS; ++j) b8[j] = b[j];
}

// ---------------------------------------------------------------------------
// Fused prep kernel (unchanged from round 4/5)
// ---------------------------------------------------------------------------
__global__ void prep_fused(const float* __restrict__ x,
                           const float* __restrict__ bw,
                           const float* __restrict__ sw,
                           const float* __restrict__ ss,
                           unsigned short* __restrict__ A,
                           unsigned short* __restrict__ Bm,
                           int nABlk) {
    if ((int)blockIdx.x < nABlk) {
        // ---- A path: idx = 4*t .. 4*t+3, all same row n (H % 4 == 0) ------
        const int t   = blockIdx.x * 256 + threadIdx.x;
        const int idx = t * 4;
        const int n   = idx >> 10;
        const int h   = idx & (H_DIM - 1);
        const float4 xv = *reinterpret_cast<const float4*>(x + idx);
        const float vs[4] = {xv.x, xv.y, xv.z, xv.w};

        u16x8 packs[4];
        u16x4 silus;
#pragma unroll
        for (int e = 0; e < 4; ++e) {
            const float v = vs[e];
            float b8[NBASIS];
            spline_bases(v, b8);
#pragma unroll
            for (int j = 0; j < NBASIS; ++j) packs[e][j] = f2bf(b8[j]);
            silus[e] = f2bf(v / (1.0f + __expf(-v)));
        }
        const size_t rowBase = (size_t)n * K_DIM;
        u16x8* dst = reinterpret_cast<u16x8*>(A + rowBase + (size_t)h * 8);
#pragma unroll
        for (int e = 0; e < 4; ++e) dst[e] = packs[e];
        *reinterpret_cast<u16x4*>(A + rowBase + K_SILU + h) = silus;
    } else {
        // ---- B path: idx = 2*t .. 2*t+1, same row o (H % 2 == 0) ----------
        const int t   = (blockIdx.x - nABlk) * 256 + threadIdx.x;
        const int idx = t * 2;
        const int o   = idx >> 10;
        const int h   = idx & (H_DIM - 1);
        const float4* p = reinterpret_cast<const float4*>(sw + (size_t)idx * 8);
        const float2 scv = *reinterpret_cast<const float2*>(ss + idx);
        const float2 bwv = *reinterpret_cast<const float2*>(bw + idx);
        const float sc[2] = {scv.x, scv.y};

        u16x8 packs[2];
#pragma unroll
        for (int e = 0; e < 2; ++e) {
            float4 w0 = p[e * 2], w1 = p[e * 2 + 1];
            packs[e][0] = f2bf(w0.x * sc[e]); packs[e][1] = f2bf(w0.y * sc[e]);
            packs[e][2] = f2bf(w0.z * sc[e]); packs[e][3] = f2bf(w0.w * sc[e]);
            packs[e][4] = f2bf(w1.x * sc[e]); packs[e][5] = f2bf(w1.y * sc[e]);
            packs[e][6] = f2bf(w1.z * sc[e]); packs[e][7] = f2bf(w1.w * sc[e]);
        }
        const size_t rowBase = (size_t)o * K_DIM;
        u16x8* dst = reinterpret_cast<u16x8*>(Bm + rowBase + (size_t)h * 8);
        dst[0] = packs[0];
        dst[1] = packs[1];
        u16x2 bwp; bwp[0] = f2bf(bwv.x); bwp[1] = f2bf(bwv.y);
        *reinterpret_cast<u16x2*>(Bm + rowBase + K_SILU + h) = bwp;
    }
}

// ---------------------------------------------------------------------------
// Kernel 3: C = gelu(A @ B^T) — 256x256 tile, 8-wave, 8-phase one-barrier
// counted-vmcnt schedule (r5 structure, 497 us), chunk-XOR conflict-free LDS,
// setprio, bijective XCD swizzle.
// Round-7 change (r6's 4-phase merge REVERTED — it regressed 497->517):
//   * READ HOISTING: each phase's ds_reads move to the TAIL of the previous
//     phase (after its MFMA cluster, same barrier interval). Validity:
//       - B1(t) in buf0.B1: staged prev iter ph3, next write this iter ph3;
//         no pending write during ph1 -> read at ph1-tail is safe, and gives
//         the ph3 stage MORE barrier separation (2 instead of 1).
//       - A1(t) in buf0.A1: next write this iter ph4; read at ph2-tail safe.
//       - mirrored for buf1 at ph5/ph6 tails.
//     Buffer-crossing reads (ph1/ph5's A0,B0) stay post-barrier: they are
//     published by the preceding vmcnt(6)+barrier and cannot move up.
//   * aF WAR: ph2's q01 MFMAs consume aF(A0) before the tail-read overwrites
//     with A1 — register dependency; reads issue under the MFMA shadow.
//   * No new registers (same aF/bF0/bF1 banks), no sync change; stage/wait
//     ledger byte-identical to r5. ph3/ph4/ph7/ph8 are read-free.
// ---------------------------------------------------------------------------
#define FENCE()      asm volatile("" ::: "memory")
#define BARRIER()    do { FENCE(); __builtin_amdgcn_s_barrier(); FENCE(); } while (0)
#define WAIT_VM6()   asm volatile("s_waitcnt vmcnt(6)" ::: "memory")

// Load NF*2 fragments (NF row-blocks x kk=0,1) from one LDS half-tile.
// Chunk-XOR swizzle: logical chunk c at row r lives in slot c ^ (r&7).
template<int NF>
__device__ __forceinline__ void load_frags(const unsigned short* hp, int rbase,
                                           int l16, int quad, bf16x8* f) {
#pragma unroll
    for (int i = 0; i < NF; ++i)
#pragma unroll
        for (int kk = 0; kk < 2; ++kk)
            f[i * 2 + kk] = *reinterpret_cast<const bf16x8*>(
                &hp[(rbase + i * 16 + l16) * 64 +
                    ((((kk << 2) + quad) ^ (l16 & 7)) << 3)]);
}

template<int QA, int QB>
__device__ __forceinline__ void mfma_quad(const bf16x8* aF, const bf16x8* bF,
                                          f32x4 (&acc)[8][4]) {
    __builtin_amdgcn_s_setprio(1);
#pragma unroll
    for (int kk = 0; kk < 2; ++kk)          // kk OUTER: no dependent pairs
#pragma unroll
        for (int m2 = 0; m2 < 4; ++m2)
#pragma unroll
            for (int n2 = 0; n2 < 2; ++n2)
                acc[QA * 4 + m2][QB * 2 + n2] =
                    __builtin_amdgcn_mfma_f32_16x16x32_bf16(
                        aF[m2 * 2 + kk], bF[n2 * 2 + kk],
                        acc[QA * 4 + m2][QB * 2 + n2], 0, 0, 0);
    __builtin_amdgcn_s_setprio(0);
}

__global__ __launch_bounds__(512, 2) void gemm_kan(
    const unsigned short* __restrict__ A,
    const unsigned short* __restrict__ B,
    float* __restrict__ out, int M, int D) {

    // 2 dbuf x {A0,A1,B0,B1} halves of 128x64 bf16 = 128 KiB
    __shared__ __align__(16) unsigned short lds[2][4][128 * 64];

    const int tid  = threadIdx.x;
    const int lane = tid & 63;
    const int w    = tid >> 6;          // wave 0..7
    const int wr   = w >> 2;            // 0..1  (M half)
    const int wc   = w & 3;             // 0..3  (N quarter)
    const int quad = lane >> 4, l16 = lane & 15;

    // T1: bijective XCD swizzle (nwg = 512, 512 % 8 == 0)
    const int nwg = gridDim.x;
    const int cpx = nwg >> 3;
    int bid = blockIdx.x;
    bid = (bid & 7) * cpx + (bid >> 3);
    const int nOB  = D / BM;            // 16
    const int mBlk = bid / nOB;
    const int oBlk = bid % nOB;

    // ---- staging geometry (verified: 0 bank conflicts) --------------------
    // Half-tile = 128 rows x 64 bf16 (16 KiB); wave w stages rows
    // [w*16, w*16+16) as 2 x global_load_lds (1024 B each, linear dest).
    // Source pre-swizzled: global chunk (lane&7)^(lane>>3) -> slot lane&7.
    // A-half q = rows {wr*128 + q*64 + [0,64)}; B-half q = {wc*64 + q*32 + [0,32)}.
    const int sub = lane >> 3;
    const int cg  = ((lane & 7) ^ sub) * 8;
    const unsigned short *sA[2][2], *sB[2][2];
#pragma unroll
    for (int h = 0; h < 2; ++h)
#pragma unroll
        for (int l = 0; l < 2; ++l) {
            const int r  = w * 16 + l * 8 + sub;          // 0..127
            const int gA = mBlk * BM + (r >> 6) * 128 + h * 64 + (r & 63);
            const int gB = oBlk * BM + (r >> 5) * 64  + h * 32 + (r & 31);
            sA[h][l] = A + (size_t)gA * K_DIM + cg;
            sB[h][l] = B + (size_t)gB * K_DIM + cg;
        }
    const int ldsOff = w * 1024;        // elements; +l*512 per load

    auto stageA = [&](int db, int h, int kt) {
#pragma unroll
        for (int l = 0; l < 2; ++l)
            __builtin_amdgcn_global_load_lds(
                (const __attribute__((address_space(1))) void*)(sA[h][l] + (size_t)kt * BK),
                (__attribute__((address_space(3))) void*)(&lds[db][h][ldsOff + l * 512]),
                16, 0, 0);
    };
    auto stageB = [&](int db, int h, int kt) {
#pragma unroll
        for (int l = 0; l < 2; ++l)
            __builtin_amdgcn_global_load_lds(
                (const __attribute__((address_space(1))) void*)(sB[h][l] + (size_t)kt * BK),
                (__attribute__((address_space(3))) void*)(&lds[db][2 + h][ldsOff + l * 512]),
                16, 0, 0);
    };

    f32x4 acc[8][4];
#pragma unroll
    for (int i = 0; i < 8; ++i)
#pragma unroll
        for (int j = 0; j < 4; ++j)
            acc[i][j] = (f32x4){0.f, 0.f, 0.f, 0.f};
    bf16x8 aF[8], bF0[4], bF1[4];

    // ---- prologue: tile0 (all 4 halves, buf0) + tile1 {A0,B1,A1} (buf1) ---
    stageA(0, 0, 0); stageB(0, 1, 0); stageA(0, 1, 0); stageB(0, 0, 0);
    stageA(1, 0, 1); stageB(1, 1, 1); stageA(1, 1, 1);
    WAIT_VM6();                          // tile0 complete; 3 halves in flight
    BARRIER();

    // ---- main loop: 2 K-tiles / iteration, 8 phases, ONE barrier each -----
    // Per-tile quadrant order: (0,0)(0,1)(1,1)(1,0). B0 in bF0 (ph1..ph4),
    // B1 in bF1 (ph1-tail..ph3). Reads hoisted one phase early (see header).
    for (int it = 0; it < NKT / 2; ++it) {
        const int t  = it << 1;                          // buf0 tile
        const int t2 = (t + 2 < NKT) ? t + 2 : NKT - 1;  // clamp keeps vmcnt
        const int t3 = (t + 3 < NKT) ? t + 3 : NKT - 1;  // counts uniform

        // ph1: read A0,B0(t); stage B0(t+1)->buf1.B0; MFMA q00; tail-read B1(t)
        load_frags<4>(&lds[0][0][0], wr * 64, l16, quad, aF);
        load_frags<2>(&lds[0][2][0], wc * 32, l16, quad, bF0);
        stageB(1, 0, t + 1);
        FENCE();
        mfma_quad<0, 0>(aF, bF0, acc);
        load_frags<2>(&lds[0][3][0], wc * 32, l16, quad, bF1);   // hoisted ph2 read
        BARRIER();

        // ph2: stage A0(t+2)->buf0.A0 (last read ph1); MFMA q01; tail-read A1(t)
        stageA(0, 0, t2);
        FENCE();
        mfma_quad<0, 1>(aF, bF1, acc);
        load_frags<4>(&lds[0][1][0], wr * 64, l16, quad, aF);    // hoisted ph3 read
        BARRIER();

        // ph3: stage B1(t+2)->buf0.B1 (last read ph1-tail); MFMA q11
        stageB(0, 1, t2);
        FENCE();
        mfma_quad<1, 1>(aF, bF1, acc);
        BARRIER();

        // ph4: stage A1(t+2)->buf0.A1 (last read ph2-tail); MFMA q10
        stageA(0, 1, t2);
        FENCE();
        mfma_quad<1, 0>(aF, bF0, acc);
        WAIT_VM6();                      // tile t+1 fully staged
        BARRIER();

        // ph5: read A0,B0(t+1) (buf1); stage B0(t+2)->buf0.B0; MFMA q00; tail B1
        load_frags<4>(&lds[1][0][0], wr * 64, l16, quad, aF);
        load_frags<2>(&lds[1][2][0], wc * 32, l16, quad, bF0);
        stageB(0, 0, t2);
        FENCE();
        mfma_quad<0, 0>(aF, bF0, acc);
        load_frags<2>(&lds[1][3][0], wc * 32, l16, quad, bF1);   // hoisted ph6 read
        BARRIER();

        // ph6: stage A0(t+3)->buf1.A0 (last read ph5); MFMA q01; tail-read A1(t+1)
        stageA(1, 0, t3);
        FENCE();
        mfma_quad<0, 1>(aF, bF1, acc);
        load_frags<4>(&lds[1][1][0], wr * 64, l16, quad, aF);    // hoisted ph7 read
        BARRIER();

        // ph7: stage B1(t+3)->buf1.B1 (last read ph5-tail); MFMA q11
        stageB(1, 1, t3);
        FENCE();
        mfma_quad<1, 1>(aF, bF1, acc);
        BARRIER();

        // ph8: stage A1(t+3)->buf1.A1 (last read ph6-tail); MFMA q10
        stageA(1, 1, t3);
        FENCE();
        mfma_quad<1, 0>(aF, bF0, acc);
        WAIT_VM6();                      // tile t+2 fully staged
        BARRIER();
    }
    asm volatile("s_waitcnt vmcnt(0)" ::: "memory");  // drain tail prefetch

    // ---- epilogue: exact (erf) GELU, fp32 store ---------------------------
    const int mBase = mBlk * BM + wr * 128;
    const int oBase = oBlk * BM + wc * 64 + l16;
#pragma unroll
    for (int mi = 0; mi < 8; ++mi) {
#pragma unroll
        for (int ni = 0; ni < 4; ++ni) {
            const int o = oBase + ni * 16;
#pragma unroll
            for (int r = 0; r < 4; ++r) {
                const int m = mBase + mi * 16 + quad * 4 + r;
                float v = acc[mi][ni][r];
                float gv = 0.5f * v * (1.0f + erff(v * 0.70710678118654752f));
                out[(size_t)m * D + o] = gv;
            }
        }
    }
}

// ---------------------------------------------------------------------------
extern "C" void kernel_launch(void* const* d_in, const int* in_sizes, int n_in,
                              void* d_out, int out_size, void* d_ws, size_t ws_size,
                              hipStream_t stream) {
    const float* x  = (const float*)d_in[0];   // (B,S,H)
    const float* bw = (const float*)d_in[1];   // (D,H)
    const float* sw = (const float*)d_in[2];   // (D,H,8)
    const float* ss = (const float*)d_in[3];   // (D,H)
    float* out = (float*)d_out;

    const int M = in_sizes[0] / H_DIM;         // 8192
    const int D = in_sizes[1] / H_DIM;         // 4096

    unsigned short* Aws = (unsigned short*)d_ws;              // M x K bf16
    unsigned short* Bws = Aws + (size_t)M * K_DIM;            // D x K bf16

    const int nABlk = (M * H_DIM / 4) / 256;   // 8192 (exact: M*H % 1024 == 0)
    const int nBBlk = (D * H_DIM / 2) / 256;   // 8192 (exact)
    prep_fused<<<nABlk + nBBlk, 256, 0, stream>>>(x, bw, sw, ss, Aws, Bws, nABlk);

    dim3 grid((M / BM) * (D / BM));            // 32*16 = 512 blocks
    gemm_kan<<<grid, 512, 0, stream>>>(Aws, Bws, out, M, D);
}

// Round 8
// 715.398 us; speedup vs baseline: 1.0411x; 1.0153x over previous
//
#include <hip/hip_runtime.h>
#include <hip/hip_bf16.h>
#include <math.h>

// Problem constants (fixed by the reference: B=4,S=2048,H=1024,D=4096)
#define H_DIM 1024
#define NBASIS 8
#define K_DIM 9216                // 8*H (spline, k=h*8+j) + H (silu, k=8192+h)
#define K_SILU 8192
#define BM 256                    // block tile (M and O)
#define BK 64                     // K tile (bf16 elements)
#define NKT (K_DIM / BK)          // 144 (even)

typedef __bf16 bf16x8 __attribute__((ext_vector_type(8)));
typedef float f32x4 __attribute__((ext_vector_type(4)));
typedef unsigned short u16x8 __attribute__((ext_vector_type(8)));
typedef unsigned short u16x4 __attribute__((ext_vector_type(4)));
typedef unsigned short u16x2 __attribute__((ext_vector_type(2)));

__device__ __forceinline__ unsigned short f2bf(float f) {
    __hip_bfloat16 h = __float2bfloat16(f);   // RNE
    return __builtin_bit_cast(unsigned short, h);
}

// Cox-de Boor cubic, knots g[i] = (i-3)*0.4f - 1.0f (fp32, exactly as the
// reference; arithmetic and order identical to the verified r0-r7 kernels).
__device__ __forceinline__ void spline_bases(float v, float* __restrict__ b8) {
    float b[11];
#pragma unroll
    for (int i = 0; i < 11; ++i) {
        const float gi  = (float)(i - 3) * 0.4f + (-1.0f);
        const float gi1 = (float)(i - 2) * 0.4f + (-1.0f);
        b[i] = (v >= gi && v < gi1) ? 1.0f : 0.0f;
    }
#pragma unroll
    for (int k = 1; k <= 3; ++k) {
#pragma unroll
        for (int i = 0; i + k < 11; ++i) {
            const float gi   = (float)(i - 3) * 0.4f + (-1.0f);
            const float gi1  = (float)(i - 2) * 0.4f + (-1.0f);
            const float gik  = (float)(i + k - 3) * 0.4f + (-1.0f);
            const float gik1 = (float)(i + k - 2) * 0.4f + (-1.0f);
            float left  = (v - gi)   * (1.0f / (gik - gi));
            float right = (gik1 - v) * (1.0f / (gik1 - gi1));
            b[i] = left * b[i] + right * b[i + 1];
        }
    }
#pragma unroll
    for (int j = 0; j < NBASIS; ++j) b8[j] = b[j];
}

// ---------------------------------------------------------------------------
// Fused prep kernel (unchanged from round 4/5)
// ---------------------------------------------------------------------------
__global__ void prep_fused(const float* __restrict__ x,
                           const float* __restrict__ bw,
                           const float* __restrict__ sw,
                           const float* __restrict__ ss,
                           unsigned short* __restrict__ A,
                           unsigned short* __restrict__ Bm,
                           int nABlk) {
    if ((int)blockIdx.x < nABlk) {
        // ---- A path: idx = 4*t .. 4*t+3, all same row n (H % 4 == 0) ------
        const int t   = blockIdx.x * 256 + threadIdx.x;
        const int idx = t * 4;
        const int n   = idx >> 10;
        const int h   = idx & (H_DIM - 1);
        const float4 xv = *reinterpret_cast<const float4*>(x + idx);
        const float vs[4] = {xv.x, xv.y, xv.z, xv.w};

        u16x8 packs[4];
        u16x4 silus;
#pragma unroll
        for (int e = 0; e < 4; ++e) {
            const float v = vs[e];
            float b8[NBASIS];
            spline_bases(v, b8);
#pragma unroll
            for (int j = 0; j < NBASIS; ++j) packs[e][j] = f2bf(b8[j]);
            silus[e] = f2bf(v / (1.0f + __expf(-v)));
        }
        const size_t rowBase = (size_t)n * K_DIM;
        u16x8* dst = reinterpret_cast<u16x8*>(A + rowBase + (size_t)h * 8);
#pragma unroll
        for (int e = 0; e < 4; ++e) dst[e] = packs[e];
        *reinterpret_cast<u16x4*>(A + rowBase + K_SILU + h) = silus;
    } else {
        // ---- B path: idx = 2*t .. 2*t+1, same row o (H % 2 == 0) ----------
        const int t   = (blockIdx.x - nABlk) * 256 + threadIdx.x;
        const int idx = t * 2;
        const int o   = idx >> 10;
        const int h   = idx & (H_DIM - 1);
        const float4* p = reinterpret_cast<const float4*>(sw + (size_t)idx * 8);
        const float2 scv = *reinterpret_cast<const float2*>(ss + idx);
        const float2 bwv = *reinterpret_cast<const float2*>(bw + idx);
        const float sc[2] = {scv.x, scv.y};

        u16x8 packs[2];
#pragma unroll
        for (int e = 0; e < 2; ++e) {
            float4 w0 = p[e * 2], w1 = p[e * 2 + 1];
            packs[e][0] = f2bf(w0.x * sc[e]); packs[e][1] = f2bf(w0.y * sc[e]);
            packs[e][2] = f2bf(w0.z * sc[e]); packs[e][3] = f2bf(w0.w * sc[e]);
            packs[e][4] = f2bf(w1.x * sc[e]); packs[e][5] = f2bf(w1.y * sc[e]);
            packs[e][6] = f2bf(w1.z * sc[e]); packs[e][7] = f2bf(w1.w * sc[e]);
        }
        const size_t rowBase = (size_t)o * K_DIM;
        u16x8* dst = reinterpret_cast<u16x8*>(Bm + rowBase + (size_t)h * 8);
        dst[0] = packs[0];
        dst[1] = packs[1];
        u16x2 bwp; bwp[0] = f2bf(bwv.x); bwp[1] = f2bf(bwv.y);
        *reinterpret_cast<u16x2*>(Bm + rowBase + K_SILU + h) = bwp;
    }
}

// ---------------------------------------------------------------------------
// Kernel 3: C = gelu(A @ B^T) — 256x256 tile, 8-wave, 8-phase one-barrier
// counted-vmcnt schedule, chunk-XOR conflict-free LDS, setprio, bijective
// XCD swizzle.
// Round-8 change vs r7 (481 us, MfmaUtil 58.9): FULL read shadowing.
// The publication wait moves from ph4/ph8 to ph3/ph7 with vmcnt(4):
//   at ph3-end outstanding = 12 (6 carried {A0,B1,A1}(t+1) + ph1 B0(t+1)
//   + ph2 A0(t+2) + ph3 B1(t+2)); oldest 8 = tile t+1 -> vmcnt(4) + barrier
//   publishes t+1 chip-wide at ph3-end (mirror: t+2 at ph7-end).
// So ph4/ph8 tails legally pre-read the NEXT tile's A0,B0 — previously the
// only unhoistable phase-head burst (cross-wave publication constraint).
// Now EVERY phase enters with MFMA operands resident; all 48 ds_reads per
// iteration issue in MFMA shadows. Steady-state carry after each wait = 4,
// +2 stage = 6 at iteration boundary, matching the prologue. Overwrite
// audit: every stage target's last ds_read is >= 1 barrier earlier
// (ph1:buf1.B0 last read prev ph4-tail; ph2:buf0.A0 prev ph8-tail;
//  ph3:buf0.B1 ph1-tail; ph4:buf0.A1 ph2-tail; ph5:buf0.B0 prev ph8-tail;
//  ph6:buf1.A0 ph4-tail; ph7:buf1.B1 ph5-tail; ph8:buf1.A1 ph6-tail).
// Register banks unchanged (aF/bF0/bF1; WAR under MFMA shadow as in r7).
// ---------------------------------------------------------------------------
#define FENCE()      asm volatile("" ::: "memory")
#define BARRIER()    do { FENCE(); __builtin_amdgcn_s_barrier(); FENCE(); } while (0)
#define WAIT_VM6()   asm volatile("s_waitcnt vmcnt(6)" ::: "memory")
#define WAIT_VM4()   asm volatile("s_waitcnt vmcnt(4)" ::: "memory")

// Load NF*2 fragments (NF row-blocks x kk=0,1) from one LDS half-tile.
// Chunk-XOR swizzle: logical chunk c at row r lives in slot c ^ (r&7).
template<int NF>
__device__ __forceinline__ void load_frags(const unsigned short* hp, int rbase,
                                           int l16, int quad, bf16x8* f) {
#pragma unroll
    for (int i = 0; i < NF; ++i)
#pragma unroll
        for (int kk = 0; kk < 2; ++kk)
            f[i * 2 + kk] = *reinterpret_cast<const bf16x8*>(
                &hp[(rbase + i * 16 + l16) * 64 +
                    ((((kk << 2) + quad) ^ (l16 & 7)) << 3)]);
}

template<int QA, int QB>
__device__ __forceinline__ void mfma_quad(const bf16x8* aF, const bf16x8* bF,
                                          f32x4 (&acc)[8][4]) {
    __builtin_amdgcn_s_setprio(1);
#pragma unroll
    for (int kk = 0; kk < 2; ++kk)          // kk OUTER: no dependent pairs
#pragma unroll
        for (int m2 = 0; m2 < 4; ++m2)
#pragma unroll
            for (int n2 = 0; n2 < 2; ++n2)
                acc[QA * 4 + m2][QB * 2 + n2] =
                    __builtin_amdgcn_mfma_f32_16x16x32_bf16(
                        aF[m2 * 2 + kk], bF[n2 * 2 + kk],
                        acc[QA * 4 + m2][QB * 2 + n2], 0, 0, 0);
    __builtin_amdgcn_s_setprio(0);
}

__global__ __launch_bounds__(512, 2) void gemm_kan(
    const unsigned short* __restrict__ A,
    const unsigned short* __restrict__ B,
    float* __restrict__ out, int M, int D) {

    // 2 dbuf x {A0,A1,B0,B1} halves of 128x64 bf16 = 128 KiB
    __shared__ __align__(16) unsigned short lds[2][4][128 * 64];

    const int tid  = threadIdx.x;
    const int lane = tid & 63;
    const int w    = tid >> 6;          // wave 0..7
    const int wr   = w >> 2;            // 0..1  (M half)
    const int wc   = w & 3;             // 0..3  (N quarter)
    const int quad = lane >> 4, l16 = lane & 15;

    // T1: bijective XCD swizzle (nwg = 512, 512 % 8 == 0)
    const int nwg = gridDim.x;
    const int cpx = nwg >> 3;
    int bid = blockIdx.x;
    bid = (bid & 7) * cpx + (bid >> 3);
    const int nOB  = D / BM;            // 16
    const int mBlk = bid / nOB;
    const int oBlk = bid % nOB;

    // ---- staging geometry (verified: 0 bank conflicts) --------------------
    // Half-tile = 128 rows x 64 bf16 (16 KiB); wave w stages rows
    // [w*16, w*16+16) as 2 x global_load_lds (1024 B each, linear dest).
    // Source pre-swizzled: global chunk (lane&7)^(lane>>3) -> slot lane&7.
    // A-half q = rows {wr*128 + q*64 + [0,64)}; B-half q = {wc*64 + q*32 + [0,32)}.
    const int sub = lane >> 3;
    const int cg  = ((lane & 7) ^ sub) * 8;
    const unsigned short *sA[2][2], *sB[2][2];
#pragma unroll
    for (int h = 0; h < 2; ++h)
#pragma unroll
        for (int l = 0; l < 2; ++l) {
            const int r  = w * 16 + l * 8 + sub;          // 0..127
            const int gA = mBlk * BM + (r >> 6) * 128 + h * 64 + (r & 63);
            const int gB = oBlk * BM + (r >> 5) * 64  + h * 32 + (r & 31);
            sA[h][l] = A + (size_t)gA * K_DIM + cg;
            sB[h][l] = B + (size_t)gB * K_DIM + cg;
        }
    const int ldsOff = w * 1024;        // elements; +l*512 per load

    auto stageA = [&](int db, int h, int kt) {
#pragma unroll
        for (int l = 0; l < 2; ++l)
            __builtin_amdgcn_global_load_lds(
                (const __attribute__((address_space(1))) void*)(sA[h][l] + (size_t)kt * BK),
                (__attribute__((address_space(3))) void*)(&lds[db][h][ldsOff + l * 512]),
                16, 0, 0);
    };
    auto stageB = [&](int db, int h, int kt) {
#pragma unroll
        for (int l = 0; l < 2; ++l)
            __builtin_amdgcn_global_load_lds(
                (const __attribute__((address_space(1))) void*)(sB[h][l] + (size_t)kt * BK),
                (__attribute__((address_space(3))) void*)(&lds[db][2 + h][ldsOff + l * 512]),
                16, 0, 0);
    };

    f32x4 acc[8][4];
#pragma unroll
    for (int i = 0; i < 8; ++i)
#pragma unroll
        for (int j = 0; j < 4; ++j)
            acc[i][j] = (f32x4){0.f, 0.f, 0.f, 0.f};
    bf16x8 aF[8], bF0[4], bF1[4];

    // ---- prologue: tile0 (all 4 halves, buf0) + tile1 {A0,B1,A1} (buf1) ---
    stageA(0, 0, 0); stageB(0, 1, 0); stageA(0, 1, 0); stageB(0, 0, 0);
    stageA(1, 0, 1); stageB(1, 1, 1); stageA(1, 1, 1);
    WAIT_VM6();                          // tile0 complete; 3 halves in flight
    BARRIER();
    // pre-load ph1 operands (steady state: done at prev ph8-tail)
    load_frags<4>(&lds[0][0][0], wr * 64, l16, quad, aF);     // A0(0)
    load_frags<2>(&lds[0][2][0], wc * 32, l16, quad, bF0);    // B0(0)

    // ---- main loop: 2 K-tiles / iteration, 8 phases, ONE barrier each -----
    // Quadrant order per tile: (0,0)(0,1)(1,1)(1,0). All MFMA operands are
    // resident at phase entry; reads are next-phase prefetch in MFMA shadow.
    for (int it = 0; it < NKT / 2; ++it) {
        const int t  = it << 1;                          // buf0 tile
        const int t2 = (t + 2 < NKT) ? t + 2 : NKT - 1;  // clamp keeps vmcnt
        const int t3 = (t + 3 < NKT) ? t + 3 : NKT - 1;  // counts uniform

        // ph1: q00(t); stage B0(t+1)->buf1.B0; tail bF1<-B1(t)
        stageB(1, 0, t + 1);
        FENCE();
        mfma_quad<0, 0>(aF, bF0, acc);
        load_frags<2>(&lds[0][3][0], wc * 32, l16, quad, bF1);
        BARRIER();

        // ph2: q01(t); stage A0(t+2)->buf0.A0; tail aF<-A1(t)
        stageA(0, 0, t2);
        FENCE();
        mfma_quad<0, 1>(aF, bF1, acc);
        load_frags<4>(&lds[0][1][0], wr * 64, l16, quad, aF);
        BARRIER();

        // ph3: q11(t); stage B1(t+2)->buf0.B1; WAIT vmcnt(4) -> tile t+1 published
        stageB(0, 1, t2);
        FENCE();
        mfma_quad<1, 1>(aF, bF1, acc);
        WAIT_VM4();
        BARRIER();

        // ph4: q10(t); stage A1(t+2)->buf0.A1; tail aF<-A0(t+1), bF0<-B0(t+1)
        stageA(0, 1, t2);
        FENCE();
        mfma_quad<1, 0>(aF, bF0, acc);
        load_frags<4>(&lds[1][0][0], wr * 64, l16, quad, aF);
        load_frags<2>(&lds[1][2][0], wc * 32, l16, quad, bF0);
        BARRIER();

        // ph5: q00(t+1); stage B0(t+2)->buf0.B0; tail bF1<-B1(t+1)
        stageB(0, 0, t2);
        FENCE();
        mfma_quad<0, 0>(aF, bF0, acc);
        load_frags<2>(&lds[1][3][0], wc * 32, l16, quad, bF1);
        BARRIER();

        // ph6: q01(t+1); stage A0(t+3)->buf1.A0; tail aF<-A1(t+1)
        stageA(1, 0, t3);
        FENCE();
        mfma_quad<0, 1>(aF, bF1, acc);
        load_frags<4>(&lds[1][1][0], wr * 64, l16, quad, aF);
        BARRIER();

        // ph7: q11(t+1); stage B1(t+3)->buf1.B1; WAIT vmcnt(4) -> t+2 published
        stageB(1, 1, t3);
        FENCE();
        mfma_quad<1, 1>(aF, bF1, acc);
        WAIT_VM4();
        BARRIER();

        // ph8: q10(t+1); stage A1(t+3)->buf1.A1; tail aF<-A0(t+2), bF0<-B0(t+2)
        stageA(1, 1, t3);
        FENCE();
        mfma_quad<1, 0>(aF, bF0, acc);
        load_frags<4>(&lds[0][0][0], wr * 64, l16, quad, aF);
        load_frags<2>(&lds[0][2][0], wc * 32, l16, quad, bF0);
        BARRIER();
    }
    asm volatile("s_waitcnt vmcnt(0)" ::: "memory");  // drain tail prefetch

    // ---- epilogue: exact (erf) GELU, fp32 store ---------------------------
    const int mBase = mBlk * BM + wr * 128;
    const int oBase = oBlk * BM + wc * 64 + l16;
#pragma unroll
    for (int mi = 0; mi < 8; ++mi) {
#pragma unroll
        for (int ni = 0; ni < 4; ++ni) {
            const int o = oBase + ni * 16;
#pragma unroll
            for (int r = 0; r < 4; ++r) {
                const int m = mBase + mi * 16 + quad * 4 + r;
                float v = acc[mi][ni][r];
                float gv = 0.5f * v * (1.0f + erff(v * 0.70710678118654752f));
                out[(size_t)m * D + o] = gv;
            }
        }
    }
}

// ---------------------------------------------------------------------------
extern "C" void kernel_launch(void* const* d_in, const int* in_sizes, int n_in,
                              void* d_out, int out_size, void* d_ws, size_t ws_size,
                              hipStream_t stream) {
    const float* x  = (const float*)d_in[0];   // (B,S,H)
    const float* bw = (const float*)d_in[1];   // (D,H)
    const float* sw = (const float*)d_in[2];   // (D,H,8)
    const float* ss = (const float*)d_in[3];   // (D,H)
    float* out = (float*)d_out;

    const int M = in_sizes[0] / H_DIM;         // 8192
    const int D = in_sizes[1] / H_DIM;         // 4096

    unsigned short* Aws = (unsigned short*)d_ws;              // M x K bf16
    unsigned short* Bws = Aws + (size_t)M * K_DIM;            // D x K bf16

    const int nABlk = (M * H_DIM / 4) / 256;   // 8192 (exact: M*H % 1024 == 0)
    const int nBBlk = (D * H_DIM / 2) / 256;   // 8192 (exact)
    prep_fused<<<nABlk + nBBlk, 256, 0, stream>>>(x, bw, sw, ss, Aws, Bws, nABlk);

    dim3 grid((M / BM) * (D / BM));            // 32*16 = 512 blocks
    gemm_kan<<<grid, 512, 0, stream>>>(Aws, Bws, out, M, D);
}